// Round 3
// baseline (514.815 us; speedup 1.0000x reference)
//
#include <hip/hip_runtime.h>

#define NC 21
#define NB 8
#define HW (512*512)
#define EPS 1e-8f
#define NREP 8
#define NTILE 256      // 1024-pixel chunks per image
#define PSTRIDE 512    // padded 441 -> 512 floats per block slice (partial path)

typedef float f32x4 __attribute__((ext_vector_type(4)));

// Round-4 theory: three structurally different kernels (VGPR 32/28/52, occ
// 57/54/38%) all ran at exactly ~275us / 650 GB/s => a HW queue limits the
// load path, not the source schedule. Little's law at wave granularity:
// 1344 wave-loads/CU over 660K cycles = 1 outstanding 1KB load per CU (~8
// lines). Plane stride is 1MB = 2^20 -> all 42 streams alias to the SAME L1
// set; ~1 outstanding miss per set * 8 sets touched per wave-load = the
// observed in-flight budget. Fix: nontemporal loads (nt bit, no L1 allocate)
// for every plane read.
// Also: replace the 441x2048 device-scope float atomics (256-way same-address
// contention, 3.9MB of RMW writes) with per-block partial stores + a reduce
// kernel (ws-size-guarded; atomic path kept as fallback).

template <bool PARTIAL>
__global__ __launch_bounds__(256) void cm_accum(const float* __restrict__ input,
                                                const float* __restrict__ target,
                                                float* __restrict__ cm /*[NB][NC][NC]*/,
                                                float* __restrict__ partial /*[NB*NTILE][PSTRIDE]*/) {
    __shared__ float scm[NREP][NC * NC];
    const int t = threadIdx.x;
    for (int i = t; i < NREP * NC * NC; i += 256) ((float*)scm)[i] = 0.0f;
    __syncthreads();

    const int b    = blockIdx.x >> 8;    // 256 tiles per batch
    const int tile = blockIdx.x & 255;
    const int q    = (tile << 8) + t;    // float4 index within a channel plane

    const f32x4* ip = (const f32x4*)(input  + (size_t)b * NC * HW);
    const f32x4* tp = (const f32x4*)(target + (size_t)b * NC * HW);
    const int plane4 = HW / 4;

    // ---- Phase 1: issue ALL 21 input loads (nontemporal), fence, argmax ----
    f32x4 v[NC];
    #pragma unroll
    for (int c = 0; c < NC; ++c) v[c] = __builtin_nontemporal_load(ip + c * plane4 + q);
    __builtin_amdgcn_sched_barrier(0);

    f32x4 m = v[0];
    int jx = 0, jy = 0, jz = 0, jw = 0;
    #pragma unroll
    for (int c = 1; c < NC; ++c) {
        if (v[c].x > m.x) { m.x = v[c].x; jx = c; }
        if (v[c].y > m.y) { m.y = v[c].y; jy = c; }
        if (v[c].z > m.z) { m.z = v[c].z; jz = c; }
        if (v[c].w > m.w) { m.w = v[c].w; jw = c; }
    }

    // ---- Phase 2: issue ALL 21 target loads (nontemporal), fence, scatter ----
    f32x4 y[NC];
    #pragma unroll
    for (int c = 0; c < NC; ++c) y[c] = __builtin_nontemporal_load(tp + c * plane4 + q);
    __builtin_amdgcn_sched_barrier(0);

    float* my = scm[t & (NREP - 1)];
    #pragma unroll
    for (int c = 0; c < NC; ++c) {
        const int row = c * NC;
        atomicAdd(&my[row + jx], y[c].x);
        atomicAdd(&my[row + jy], y[c].y);
        atomicAdd(&my[row + jz], y[c].z);
        atomicAdd(&my[row + jw], y[c].w);
    }
    __syncthreads();

    if (PARTIAL) {
        // contention-free flush: coalesced stores to this block's own slice
        float* pout = partial + (size_t)blockIdx.x * PSTRIDE;
        for (int i = t; i < PSTRIDE; i += 256) {
            float s = 0.0f;
            if (i < NC * NC) {
                #pragma unroll
                for (int r = 0; r < NREP; ++r) s += scm[r][i];
            }
            pout[i] = s;   // pad region written as 0 so reduce needs no guards
        }
    } else {
        // fallback: global atomics (requires pre-zeroed cm)
        for (int i = t; i < NC * NC; i += 256) {
            float s = 0.0f;
            #pragma unroll
            for (int r = 0; r < NREP; ++r) s += scm[r][i];
            atomicAdd(&cm[b * NC * NC + i], s);
        }
    }
}

// partial[b*NTILE + s][e] summed over s -> cm[b][e]. 8 blocks, coalesced:
// thread t reads entries t and t+256 of each 512-float slice.
__global__ __launch_bounds__(256) void cm_reduce(const float* __restrict__ partial,
                                                 float* __restrict__ cm) {
    const int b = blockIdx.x, t = threadIdx.x;
    const float* p = partial + (size_t)b * NTILE * PSTRIDE;
    float s0 = 0.0f, s1 = 0.0f;
    #pragma unroll 8
    for (int s = 0; s < NTILE; ++s) {
        s0 += p[(size_t)s * PSTRIDE + t];
        s1 += p[(size_t)s * PSTRIDE + t + 256];
    }
    cm[b * NC * NC + t] = s0;
    if (t + 256 < NC * NC) cm[b * NC * NC + t + 256] = s1;
}

// rowsum[b,i] = sum_j cm[b,i,j]; out[i,j] = mean_b cm[b,i,j]/(rowsum[b,i]+EPS)
__global__ __launch_bounds__(512) void cm_final(const float* __restrict__ cm,
                                                float* __restrict__ out) {
    __shared__ float rs[NB * NC];
    const int t = threadIdx.x;
    if (t < NB * NC) {
        const int b = t / NC, i = t % NC;
        float s = 0.0f;
        for (int j = 0; j < NC; ++j) s += cm[b * NC * NC + i * NC + j];
        rs[t] = s + EPS;
    }
    __syncthreads();
    if (t < NC * NC) {
        const int i = t / NC;
        float acc = 0.0f;
        for (int b = 0; b < NB; ++b) acc += cm[b * NC * NC + t] / rs[b * NC + i];
        out[t] = acc * (1.0f / NB);
    }
}

extern "C" void kernel_launch(void* const* d_in, const int* in_sizes, int n_in,
                              void* d_out, int out_size, void* d_ws, size_t ws_size,
                              hipStream_t stream) {
    const float* input  = (const float*)d_in[0];
    const float* target = (const float*)d_in[1];
    float* out = (float*)d_out;

    const size_t partial_floats = (size_t)NB * NTILE * PSTRIDE;   // 1M floats = 4 MB
    const size_t need = (partial_floats + NB * NC * NC) * sizeof(float);

    if (ws_size >= need) {
        float* partial = (float*)d_ws;
        float* cm      = partial + partial_floats;
        cm_accum<true><<<NB * NTILE, 256, 0, stream>>>(input, target, cm, partial);
        cm_reduce<<<NB, 256, 0, stream>>>(partial, cm);
        cm_final<<<1, 512, 0, stream>>>(cm, out);
    } else {
        float* cm = (float*)d_ws;   // NB*NC*NC floats
        hipMemsetAsync(cm, 0, NB * NC * NC * sizeof(float), stream);
        cm_accum<false><<<NB * NTILE, 256, 0, stream>>>(input, target, cm, nullptr);
        cm_final<<<1, 512, 0, stream>>>(cm, out);
    }
}